// Round 2
// baseline (328.029 us; speedup 1.0000x reference)
//
#include <hip/hip_runtime.h>
#include <math.h>

#define HID 4096
#define NEXP 64
#define NTOK (4 * 4096)   // B*S = 16384 tokens
#define BM 64
#define BK 64

// Fused: logits (fp64 accum) -> softmax -> descending sort -> cumsum ->
// dynamic-k select. One block = 64 tokens; 256 threads = 4 waves.
__global__ __launch_bounds__(256) void router_kernel(
    const float* __restrict__ x, const float* __restrict__ W,
    const float* __restrict__ b, float* __restrict__ out_exp,
    float* __restrict__ out_prob, float* __restrict__ out_k) {
  __shared__ float xs[BM][BK];      // 16 KB
  __shared__ float ws[BK][NEXP];    // 16 KB
  __shared__ double lgs[BM][NEXP];  // 32 KB

  const int t  = threadIdx.x;
  const int tx = t & 15;   // expert group: experts 4*tx .. 4*tx+3
  const int ty = t >> 4;   // token group: tokens  4*ty .. 4*ty+3
  const int m0 = blockIdx.x * BM;

  // ---------------- Phase 1: GEMM with fp64 accumulation ----------------
  double acc[4][4] = {{0.0}};

  for (int kb = 0; kb < HID; kb += BK) {
#pragma unroll
    for (int i = 0; i < 4; ++i) {
      int l = t + 256 * i;
      int row = l >> 4, c4 = (l & 15) * 4;
      *(float4*)&xs[row][c4] =
          *(const float4*)&x[(size_t)(m0 + row) * HID + kb + c4];
    }
#pragma unroll
    for (int i = 0; i < 4; ++i) {
      int l = t + 256 * i;
      int row = l >> 4, c4 = (l & 15) * 4;
      *(float4*)&ws[row][c4] =
          *(const float4*)&W[(size_t)(kb + row) * NEXP + c4];
    }
    __syncthreads();

#pragma unroll
    for (int k = 0; k < BK; ++k) {
      double wv[4], xv[4];
      {
        float tmp[4];
        *(float4*)tmp = *(const float4*)&ws[k][tx * 4];
#pragma unroll
        for (int j = 0; j < 4; ++j) wv[j] = (double)tmp[j];
      }
#pragma unroll
      for (int i = 0; i < 4; ++i) xv[i] = (double)xs[ty * 4 + i][k];
#pragma unroll
      for (int i = 0; i < 4; ++i)
#pragma unroll
        for (int j = 0; j < 4; ++j)
          acc[i][j] = fma(xv[i], wv[j], acc[i][j]);
    }
    __syncthreads();
  }

  // park logits (+bias) in LDS, [token][expert]
#pragma unroll
  for (int i = 0; i < 4; ++i)
#pragma unroll
    for (int j = 0; j < 4; ++j)
      lgs[ty * 4 + i][tx * 4 + j] = acc[i][j] + (double)b[tx * 4 + j];
  __syncthreads();

  // ---------------- Phase 2: routing, one wave per token ----------------
  const int wave = t >> 6;
  const int lane = t & 63;

  for (int it = 0; it < BM / 4; ++it) {
    const int tl = wave * (BM / 4) + it;
    double lgv = lgs[tl][lane];

    // softmax (fp64) across the wave
    double mx = lgv;
#pragma unroll
    for (int off = 32; off; off >>= 1) mx = fmax(mx, __shfl_xor(mx, off));
    double ev = exp(lgv - mx);
    double sm = ev;
#pragma unroll
    for (int off = 32; off; off >>= 1) sm += __shfl_xor(sm, off);
    double p = ev / sm;

    // bitonic sort: descending by p, ties by ascending index
    double sp = p;
    int    si = lane;
#pragma unroll
    for (int k = 2; k <= 64; k <<= 1) {
#pragma unroll
      for (int j = k >> 1; j > 0; j >>= 1) {
        double op = __shfl_xor(sp, j);
        int    oi = __shfl_xor(si, j);
        bool cmp  = (sp > op) || (sp == op && si < oi);
        bool keep = (cmp == (((lane & k) == 0) == ((lane & j) == 0)));
        if (!keep) { sp = op; si = oi; }
      }
    }

    // inclusive prefix sum (Kogge-Stone, fp64)
    double c = sp;
#pragma unroll
    for (int off = 1; off < 64; off <<= 1) {
      double tp = __shfl_up(c, off);
      if (lane >= off) c += tp;
    }

    unsigned long long m = __ballot(c >= 0.8);
    int kv = (m == 0ULL) ? NEXP : __ffsll(m);

    bool sel = lane < kv;
    size_t base = (size_t)(m0 + tl) * NEXP;
    out_exp[base + lane]  = sel ? (float)si : -1.0f;
    out_prob[base + lane] = sel ? (float)sp : 0.0f;
    if (lane == 0) out_k[m0 + tl] = (float)kv;
  }
}

extern "C" void kernel_launch(void* const* d_in, const int* in_sizes, int n_in,
                              void* d_out, int out_size, void* d_ws,
                              size_t ws_size, hipStream_t stream) {
  const float* x = (const float*)d_in[0];
  const float* W = (const float*)d_in[1];
  const float* b = (const float*)d_in[2];

  float* out_exp  = (float*)d_out;                   // [B,S,E]
  float* out_prob = out_exp + (size_t)NTOK * NEXP;   // [B,S,E]
  float* out_k    = out_prob + (size_t)NTOK * NEXP;  // [B,S]

  router_kernel<<<NTOK / BM, 256, 0, stream>>>(x, W, b, out_exp, out_prob,
                                               out_k);
}

// Round 3
// 301.220 us; speedup vs baseline: 1.0890x; 1.0890x over previous
//
#include <hip/hip_runtime.h>
#include <math.h>

#define HID 4096
#define NEXP 64
#define NTOK 16384
#define BM 32
#define BK 64
#define XPAD 68   // +4 float pad: breaks bank aliasing, keeps 16B alignment

// ---------------- Kernel A: fp32-bulk GEMM (fp64 chunk accum) + routing -----
__global__ __launch_bounds__(256) void router_main(
    const float* __restrict__ x, const float* __restrict__ W,
    const float* __restrict__ b, float* __restrict__ out_exp,
    float* __restrict__ out_prob, float* __restrict__ out_k,
    unsigned char* __restrict__ flags) {
  __shared__ float xs[BM][XPAD];      // 8.5 KB
  __shared__ float ws[BK][NEXP];      // 16 KB
  __shared__ double lgs[BM][NEXP];    // 16 KB

  const int t  = threadIdx.x;
  const int tx = t & 15;   // experts 4*tx .. 4*tx+3
  const int ty = t >> 4;   // tokens  2*ty .. 2*ty+1
  const int m0 = blockIdx.x * BM;

  double acc64[2][4] = {{0.0}};

  for (int kb = 0; kb < HID; kb += BK) {
    // stage x tile: 32x64 = 512 float4
#pragma unroll
    for (int i = 0; i < 2; ++i) {
      int l = t + 256 * i;
      int row = l >> 4, c4 = (l & 15) * 4;
      *(float4*)&xs[row][c4] =
          *(const float4*)&x[(size_t)(m0 + row) * HID + kb + c4];
    }
    // stage W tile: 64x64 = 1024 float4, natural [k][e] layout
#pragma unroll
    for (int i = 0; i < 4; ++i) {
      int l = t + 256 * i;
      int row = l >> 4, c4 = (l & 15) * 4;
      *(float4*)&ws[row][c4] =
          *(const float4*)&W[(size_t)(kb + row) * NEXP + c4];
    }
    __syncthreads();

    float acc[2][4] = {{0.f}};
#pragma unroll
    for (int k4 = 0; k4 < BK; k4 += 4) {
      float4 xr[2], wr[4];
#pragma unroll
      for (int i = 0; i < 2; ++i)
        xr[i] = *(const float4*)&xs[ty * 2 + i][k4];
#pragma unroll
      for (int kk = 0; kk < 4; ++kk)
        wr[kk] = *(const float4*)&ws[k4 + kk][tx * 4];
#pragma unroll
      for (int kk = 0; kk < 4; ++kk) {
        float wv[4] = {wr[kk].x, wr[kk].y, wr[kk].z, wr[kk].w};
#pragma unroll
        for (int i = 0; i < 2; ++i) {
          float xv = ((const float*)&xr[i])[kk];
#pragma unroll
          for (int j = 0; j < 4; ++j)
            acc[i][j] = fmaf(xv, wv[j], acc[i][j]);
        }
      }
    }
    // flush fp32 chunk into fp64 accumulator (kills accumulation drift)
#pragma unroll
    for (int i = 0; i < 2; ++i)
#pragma unroll
      for (int j = 0; j < 4; ++j) acc64[i][j] += (double)acc[i][j];
    __syncthreads();
  }

#pragma unroll
  for (int i = 0; i < 2; ++i)
#pragma unroll
    for (int j = 0; j < 4; ++j)
      lgs[ty * 2 + i][tx * 4 + j] = acc64[i][j] + (double)b[tx * 4 + j];
  __syncthreads();

  // ---------------- routing, one wave per token ----------------
  const int wave = t >> 6;
  const int lane = t & 63;

  for (int it = 0; it < BM / 4; ++it) {
    const int tl = wave * (BM / 4) + it;
    double lgv = lgs[tl][lane];

    double mx = lgv;
#pragma unroll
    for (int off = 32; off; off >>= 1) mx = fmax(mx, __shfl_xor(mx, off));
    double ev = exp(lgv - mx);
    double sm = ev;
#pragma unroll
    for (int off = 32; off; off >>= 1) sm += __shfl_xor(sm, off);
    double p = ev / sm;

    double sp = p;
    int    si = lane;
#pragma unroll
    for (int k = 2; k <= 64; k <<= 1) {
#pragma unroll
      for (int j = k >> 1; j > 0; j >>= 1) {
        double op = __shfl_xor(sp, j);
        int    oi = __shfl_xor(si, j);
        bool cmp  = (sp > op) || (sp == op && si < oi);
        bool keep = (cmp == (((lane & k) == 0) == ((lane & j) == 0)));
        if (!keep) { sp = op; si = oi; }
      }
    }

    double c = sp;
#pragma unroll
    for (int off = 1; off < 64; off <<= 1) {
      double tp = __shfl_up(c, off);
      if (lane >= off) c += tp;
    }

    unsigned long long m = __ballot(c >= 0.8);
    int kv = (m == 0ULL) ? NEXP : __ffsll(m);

    // ambiguity flag: near-tie among positions <= kv, or cum near threshold
    double spn = __shfl_down(sp, 1);
    bool pairRisk = (lane < kv) && (lane < 63) &&
                    ((sp - spn) < 1e-3 * (sp + spn));
    bool cumRisk  = fabs(c - 0.8) < 3e-4;
    bool flagged  = (__ballot(pairRisk || cumRisk) != 0ULL);

    bool sel = lane < kv;
    size_t base = (size_t)(m0 + tl) * NEXP;
    out_exp[base + lane]  = sel ? (float)si : -1.0f;
    out_prob[base + lane] = sel ? (float)sp : 0.0f;
    if (lane == 0) {
      out_k[m0 + tl] = (float)kv;
      flags[m0 + tl] = flagged ? 1 : 0;
    }
  }
}

// ---------------- Kernel B: fp64 repair of flagged tokens -------------------
__global__ __launch_bounds__(256) void router_repair(
    const float* __restrict__ x, const float* __restrict__ W,
    const float* __restrict__ b, const unsigned char* __restrict__ flags,
    float* __restrict__ out_exp, float* __restrict__ out_prob,
    float* __restrict__ out_k) {
  __shared__ double part[4][NEXP];
  const int t = threadIdx.x;
  const int e = t & 63;   // expert
  const int c = t >> 6;   // K chunk (4 x 1024)

  for (int tl = 0; tl < 64; ++tl) {
    const int tok = blockIdx.x * 64 + tl;
    if (!flags[tok]) continue;  // uniform across block

    const float* xrow = x + (size_t)tok * HID;
    double s = 0.0;
    const int k0 = c * (HID / 4);
#pragma unroll 8
    for (int k = k0; k < k0 + HID / 4; ++k)
      s = fma((double)xrow[k], (double)W[(size_t)k * NEXP + e], s);
    part[c][e] = s;
    __syncthreads();

    if (t < 64) {  // wave 0, lane = e
      double lgv = ((part[0][e] + part[1][e]) + part[2][e]) + part[3][e] +
                   (double)b[e];

      double mx = lgv;
#pragma unroll
      for (int off = 32; off; off >>= 1) mx = fmax(mx, __shfl_xor(mx, off));
      double ev = exp(lgv - mx);
      double sm = ev;
#pragma unroll
      for (int off = 32; off; off >>= 1) sm += __shfl_xor(sm, off);
      double p = ev / sm;

      double sp = p;
      int    si = e;
#pragma unroll
      for (int k = 2; k <= 64; k <<= 1) {
#pragma unroll
        for (int j = k >> 1; j > 0; j >>= 1) {
          double op = __shfl_xor(sp, j);
          int    oi = __shfl_xor(si, j);
          bool cmp  = (sp > op) || (sp == op && si < oi);
          bool keep = (cmp == (((e & k) == 0) == ((e & j) == 0)));
          if (!keep) { sp = op; si = oi; }
        }
      }

      double cc = sp;
#pragma unroll
      for (int off = 1; off < 64; off <<= 1) {
        double tp = __shfl_up(cc, off);
        if (e >= off) cc += tp;
      }

      unsigned long long m = __ballot(cc >= 0.8);
      int kv = (m == 0ULL) ? NEXP : __ffsll(m);

      bool sel = e < kv;
      size_t base = (size_t)tok * NEXP;
      out_exp[base + e]  = sel ? (float)si : -1.0f;
      out_prob[base + e] = sel ? (float)sp : 0.0f;
      if (e == 0) out_k[tok] = (float)kv;
    }
    __syncthreads();
  }
}

extern "C" void kernel_launch(void* const* d_in, const int* in_sizes, int n_in,
                              void* d_out, int out_size, void* d_ws,
                              size_t ws_size, hipStream_t stream) {
  const float* x = (const float*)d_in[0];
  const float* W = (const float*)d_in[1];
  const float* b = (const float*)d_in[2];

  float* out_exp  = (float*)d_out;                   // [B,S,E]
  float* out_prob = out_exp + (size_t)NTOK * NEXP;   // [B,S,E]
  float* out_k    = out_prob + (size_t)NTOK * NEXP;  // [B,S]

  unsigned char* flags = (unsigned char*)d_ws;       // 16 KB

  router_main<<<NTOK / BM, 256, 0, stream>>>(x, W, b, out_exp, out_prob,
                                             out_k, flags);
  router_repair<<<256, 256, 0, stream>>>(x, W, b, flags, out_exp, out_prob,
                                         out_k);
}

// Round 4
// 278.590 us; speedup vs baseline: 1.1775x; 1.0812x over previous
//
#include <hip/hip_runtime.h>
#include <math.h>

#define HID 4096
#define NEXP 64
#define NTOK 16384
#define BM 32
#define BK 32
#define XPAD 36   // 32 + 4 pad: conflict-free strided rows, keeps 16B align

// ---------------- Kernel A: fp32-bulk GEMM (fp64 chunk accum) + routing -----
__global__ __launch_bounds__(256, 5) void router_main(
    const float* __restrict__ x, const float* __restrict__ W,
    const float* __restrict__ b, float* __restrict__ out_exp,
    float* __restrict__ out_prob, float* __restrict__ out_k,
    unsigned int* __restrict__ flag_count, int* __restrict__ flag_list) {
  __shared__ float xs[BM][XPAD];      // 4.5 KB
  __shared__ float ws[BK][NEXP];      // 8 KB
  __shared__ double lgs[BM][NEXP];    // 16 KB

  const int t  = threadIdx.x;
  const int tx = t & 15;   // experts 4*tx .. 4*tx+3
  const int ty = t >> 4;   // tokens  2*ty .. 2*ty+1
  const int m0 = blockIdx.x * BM;

  double acc64[2][4] = {{0.0}};

  for (int kb = 0; kb < HID; kb += BK) {
    // stage x tile: 32x32 = 256 float4 (1 per thread)
    {
      int row = t >> 3, c4 = (t & 7) * 4;
      *(float4*)&xs[row][c4] =
          *(const float4*)&x[(size_t)(m0 + row) * HID + kb + c4];
    }
    // stage W tile: 32x64 = 512 float4 (2 per thread), natural [k][e]
#pragma unroll
    for (int i = 0; i < 2; ++i) {
      int l = t + 256 * i;
      int row = l >> 4, c4 = (l & 15) * 4;
      *(float4*)&ws[row][c4] =
          *(const float4*)&W[(size_t)(kb + row) * NEXP + c4];
    }
    __syncthreads();

    float acc[2][4] = {{0.f}};
#pragma unroll
    for (int k4 = 0; k4 < BK; k4 += 4) {
      float4 xr[2], wr[4];
#pragma unroll
      for (int i = 0; i < 2; ++i)
        xr[i] = *(const float4*)&xs[ty * 2 + i][k4];
#pragma unroll
      for (int kk = 0; kk < 4; ++kk)
        wr[kk] = *(const float4*)&ws[k4 + kk][tx * 4];
#pragma unroll
      for (int kk = 0; kk < 4; ++kk) {
        float wv[4] = {wr[kk].x, wr[kk].y, wr[kk].z, wr[kk].w};
#pragma unroll
        for (int i = 0; i < 2; ++i) {
          float xv = ((const float*)&xr[i])[kk];
#pragma unroll
          for (int j = 0; j < 4; ++j)
            acc[i][j] = fmaf(xv, wv[j], acc[i][j]);
        }
      }
    }
    // flush fp32 chunk into fp64 accumulator (kills accumulation drift)
#pragma unroll
    for (int i = 0; i < 2; ++i)
#pragma unroll
      for (int j = 0; j < 4; ++j) acc64[i][j] += (double)acc[i][j];
    __syncthreads();
  }

#pragma unroll
  for (int i = 0; i < 2; ++i)
#pragma unroll
    for (int j = 0; j < 4; ++j)
      lgs[ty * 2 + i][tx * 4 + j] = acc64[i][j] + (double)b[tx * 4 + j];
  __syncthreads();

  // ---------------- routing, one wave per token ----------------
  const int wave = t >> 6;
  const int lane = t & 63;

  for (int it = 0; it < BM / 4; ++it) {
    const int tl = wave * (BM / 4) + it;
    double lgv = lgs[tl][lane];

    double mx = lgv;
#pragma unroll
    for (int off = 32; off; off >>= 1) mx = fmax(mx, __shfl_xor(mx, off));
    double ev = exp(lgv - mx);
    double sm = ev;
#pragma unroll
    for (int off = 32; off; off >>= 1) sm += __shfl_xor(sm, off);
    double p = ev / sm;

    // bitonic sort: descending by p, ties by ascending index
    double sp = p;
    int    si = lane;
#pragma unroll
    for (int k = 2; k <= 64; k <<= 1) {
#pragma unroll
      for (int j = k >> 1; j > 0; j >>= 1) {
        double op = __shfl_xor(sp, j);
        int    oi = __shfl_xor(si, j);
        bool cmp  = (sp > op) || (sp == op && si < oi);
        bool keep = (cmp == (((lane & k) == 0) == ((lane & j) == 0)));
        if (!keep) { sp = op; si = oi; }
      }
    }

    // inclusive prefix sum (Kogge-Stone, fp64)
    double c = sp;
#pragma unroll
    for (int off = 1; off < 64; off <<= 1) {
      double tp = __shfl_up(c, off);
      if (lane >= off) c += tp;
    }

    unsigned long long m = __ballot(c >= 0.8);
    int kv = (m == 0ULL) ? NEXP : __ffsll(m);

    // ambiguity flag: near-tie among positions <= kv, or cum near threshold
    // (fp32-chunk logit error ~4e-7 absolute; margins give >500x headroom)
    double spn = __shfl_down(sp, 1);
    bool pairRisk = (lane < kv) && (lane < 63) &&
                    ((sp - spn) < 1e-3 * (sp + spn));
    bool cumRisk  = fabs(c - 0.8) < 3e-4;
    bool flagged  = (__ballot(pairRisk || cumRisk) != 0ULL);

    bool sel = lane < kv;
    size_t base = (size_t)(m0 + tl) * NEXP;
    out_exp[base + lane]  = sel ? (float)si : -1.0f;
    out_prob[base + lane] = sel ? (float)sp : 0.0f;
    if (lane == 0) {
      out_k[m0 + tl] = (float)kv;
      if (flagged) {
        unsigned int idx = atomicAdd(flag_count, 1u);
        flag_list[idx] = m0 + tl;
      }
    }
  }
}

// ---------------- Kernel B: fp64 repair of flagged tokens (compact list) ----
__global__ __launch_bounds__(256) void router_repair(
    const float* __restrict__ x, const float* __restrict__ W,
    const float* __restrict__ b, const unsigned int* __restrict__ flag_count,
    const int* __restrict__ flag_list, float* __restrict__ out_exp,
    float* __restrict__ out_prob, float* __restrict__ out_k) {
  __shared__ double part[4][NEXP];
  const int t = threadIdx.x;
  const int e = t & 63;   // expert
  const int c = t >> 6;   // K chunk (4 x 1024)
  const int n = (int)*flag_count;

  for (int i = blockIdx.x; i < n; i += gridDim.x) {
    const int tok = flag_list[i];

    const float* xrow = x + (size_t)tok * HID;
    double s = 0.0;
    const int k0 = c * (HID / 4);
#pragma unroll 8
    for (int k = k0; k < k0 + HID / 4; ++k)
      s = fma((double)xrow[k], (double)W[(size_t)k * NEXP + e], s);
    part[c][e] = s;
    __syncthreads();

    if (t < 64) {  // wave 0, lane = e
      double lgv = ((part[0][e] + part[1][e]) + part[2][e]) + part[3][e] +
                   (double)b[e];

      double mx = lgv;
#pragma unroll
      for (int off = 32; off; off >>= 1) mx = fmax(mx, __shfl_xor(mx, off));
      double ev = exp(lgv - mx);
      double sm = ev;
#pragma unroll
      for (int off = 32; off; off >>= 1) sm += __shfl_xor(sm, off);
      double p = ev / sm;

      double sp = p;
      int    si = e;
#pragma unroll
      for (int k = 2; k <= 64; k <<= 1) {
#pragma unroll
        for (int j = k >> 1; j > 0; j >>= 1) {
          double op = __shfl_xor(sp, j);
          int    oi = __shfl_xor(si, j);
          bool cmp  = (sp > op) || (sp == op && si < oi);
          bool keep = (cmp == (((e & k) == 0) == ((e & j) == 0)));
          if (!keep) { sp = op; si = oi; }
        }
      }

      double cc = sp;
#pragma unroll
      for (int off = 1; off < 64; off <<= 1) {
        double tp = __shfl_up(cc, off);
        if (e >= off) cc += tp;
      }

      unsigned long long m = __ballot(cc >= 0.8);
      int kv = (m == 0ULL) ? NEXP : __ffsll(m);

      bool sel = e < kv;
      size_t base = (size_t)tok * NEXP;
      out_exp[base + e]  = sel ? (float)si : -1.0f;
      out_prob[base + e] = sel ? (float)sp : 0.0f;
      if (e == 0) out_k[tok] = (float)kv;
    }
    __syncthreads();
  }
}

extern "C" void kernel_launch(void* const* d_in, const int* in_sizes, int n_in,
                              void* d_out, int out_size, void* d_ws,
                              size_t ws_size, hipStream_t stream) {
  const float* x = (const float*)d_in[0];
  const float* W = (const float*)d_in[1];
  const float* b = (const float*)d_in[2];

  float* out_exp  = (float*)d_out;                   // [B,S,E]
  float* out_prob = out_exp + (size_t)NTOK * NEXP;   // [B,S,E]
  float* out_k    = out_prob + (size_t)NTOK * NEXP;  // [B,S]

  unsigned int* flag_count = (unsigned int*)d_ws;            // 4 B
  int*          flag_list  = (int*)((char*)d_ws + 256);      // up to 64 KB

  hipMemsetAsync(d_ws, 0, 4, stream);

  router_main<<<NTOK / BM, 256, 0, stream>>>(x, W, b, out_exp, out_prob,
                                             out_k, flag_count, flag_list);
  router_repair<<<128, 256, 0, stream>>>(x, W, b, flag_count, flag_list,
                                         out_exp, out_prob, out_k);
}

// Round 5
// 185.729 us; speedup vs baseline: 1.7662x; 1.5000x over previous
//
#include <hip/hip_runtime.h>
#include <math.h>

#define HID 4096
#define NEXP 64
#define NTOK 16384

typedef __attribute__((ext_vector_type(8))) short short8;
typedef __attribute__((ext_vector_type(8))) __bf16 bf16x8;
typedef __attribute__((ext_vector_type(4))) float f32x4;

__device__ __forceinline__ unsigned short f2bf(float f) {
  union { float f; unsigned u; } v; v.f = f;
  unsigned r = v.u + 0x7fffu + ((v.u >> 16) & 1u);  // RNE
  return (unsigned short)(r >> 16);
}
__device__ __forceinline__ float bf2f(unsigned short h) {
  union { unsigned u; float f; } v; v.u = ((unsigned)h) << 16;
  return v.f;
}

// ---- Kernel 0: convert W[k][e] fp32 -> hi/lo bf16 in B-fragment-linear order
// Wfrag[((ks*4 + nt)*64 + lane)*8 + j] = W[ks*32 + (lane>>4)*8 + j][nt*16 + (lane&15)]
__global__ __launch_bounds__(256) void wfrag_kernel(
    const float* __restrict__ W, short* __restrict__ wfh,
    short* __restrict__ wfl) {
  int gid = blockIdx.x * 256 + threadIdx.x;  // 0 .. 32767
  int l  = gid & 63;
  int nt = (gid >> 6) & 3;
  int ks = gid >> 8;                         // 0 .. 127
  int e  = nt * 16 + (l & 15);
  int k0 = ks * 32 + (l >> 4) * 8;
  short8 h8, l8;
#pragma unroll
  for (int j = 0; j < 8; ++j) {
    float w = W[(size_t)(k0 + j) * NEXP + e];
    unsigned short h = f2bf(w);
    h8[j] = (short)h;
    l8[j] = (short)f2bf(w - bf2f(h));
  }
  ((short8*)wfh)[gid] = h8;
  ((short8*)wfl)[gid] = l8;
}

// ---- Kernel 1: MFMA GEMM (LDS-free, barrier-free) + fp32 routing ----------
__global__ __launch_bounds__(256) void router_main(
    const float* __restrict__ x, const short* __restrict__ wfh,
    const short* __restrict__ wfl, const float* __restrict__ b,
    float* __restrict__ out_exp, float* __restrict__ out_prob,
    float* __restrict__ out_k, unsigned int* __restrict__ flag_count,
    int* __restrict__ flag_list) {
  __shared__ float lgs[64][65];  // 16.6 KB, pad 65 = conflict-free

  const int t = threadIdx.x;
  const int w = t >> 6;    // wave 0..3 -> token sub-tile
  const int l = t & 63;    // lane
  const int m0 = blockIdx.x * 64 + w * 16;  // wave's 16 tokens

  // A-frag source: row = m0 + (l&15), k = ks*32 + (l>>4)*8 + j
  const float* xptr = x + (size_t)(m0 + (l & 15)) * HID + (l >> 4) * 8;
  const short8* wfh8 = (const short8*)wfh;
  const short8* wfl8 = (const short8*)wfl;

  f32x4 acc1[4], acc2[4];
#pragma unroll
  for (int nt = 0; nt < 4; ++nt) {
    acc1[nt] = (f32x4){0.f, 0.f, 0.f, 0.f};
    acc2[nt] = (f32x4){0.f, 0.f, 0.f, 0.f};
  }

#pragma unroll 2
  for (int ks = 0; ks < HID / 32; ++ks) {
    float xv[8];
    *(float4*)&xv[0] = *(const float4*)(xptr + ks * 32);
    *(float4*)&xv[4] = *(const float4*)(xptr + ks * 32 + 4);
    short8 ahs, als;
#pragma unroll
    for (int j = 0; j < 8; ++j) {
      unsigned short h = f2bf(xv[j]);
      ahs[j] = (short)h;
      als[j] = (short)f2bf(xv[j] - bf2f(h));
    }
    bf16x8 ah = __builtin_bit_cast(bf16x8, ahs);
    bf16x8 al = __builtin_bit_cast(bf16x8, als);
    const int wbase = ks * 4 * 64 + l;
#pragma unroll
    for (int nt = 0; nt < 4; ++nt) {
      bf16x8 bh = __builtin_bit_cast(bf16x8, wfh8[wbase + nt * 64]);
      bf16x8 bl = __builtin_bit_cast(bf16x8, wfl8[wbase + nt * 64]);
      acc1[nt] = __builtin_amdgcn_mfma_f32_16x16x32_bf16(ah, bh, acc1[nt], 0, 0, 0);
      acc2[nt] = __builtin_amdgcn_mfma_f32_16x16x32_bf16(al, bh, acc2[nt], 0, 0, 0);
      acc2[nt] = __builtin_amdgcn_mfma_f32_16x16x32_bf16(ah, bl, acc2[nt], 0, 0, 0);
      acc2[nt] = __builtin_amdgcn_mfma_f32_16x16x32_bf16(al, bl, acc2[nt], 0, 0, 0);
    }
  }

  // D layout: row (token) = (l>>4)*4 + r, col (expert) = nt*16 + (l&15)
#pragma unroll
  for (int nt = 0; nt < 4; ++nt) {
    float bias = b[nt * 16 + (l & 15)];
#pragma unroll
    for (int r = 0; r < 4; ++r)
      lgs[w * 16 + (l >> 4) * 4 + r][nt * 16 + (l & 15)] =
          acc1[nt][r] + acc2[nt][r] + bias;
  }
  // lgs rows of wave w are written only by wave w -> no __syncthreads needed;
  // compiler inserts lgkmcnt waits before the reads below.

  // ---------------- routing (fp32; fp64 repair net catches close calls) ----
  for (int it = 0; it < 16; ++it) {
    const int tl = w * 16 + it;
    float lgv = lgs[tl][l];

    float mx = lgv;
#pragma unroll
    for (int off = 32; off; off >>= 1) mx = fmaxf(mx, __shfl_xor(mx, off));
    float ev = expf(lgv - mx);
    float sm = ev;
#pragma unroll
    for (int off = 32; off; off >>= 1) sm += __shfl_xor(sm, off);
    float p = ev / sm;

    // bitonic sort: descending by p, ties by ascending index
    float sp = p;
    int   si = l;
#pragma unroll
    for (int k = 2; k <= 64; k <<= 1) {
#pragma unroll
      for (int j = k >> 1; j > 0; j >>= 1) {
        float op = __shfl_xor(sp, j);
        int   oi = __shfl_xor(si, j);
        bool cmp  = (sp > op) || (sp == op && si < oi);
        bool keep = (cmp == (((l & k) == 0) == ((l & j) == 0)));
        if (!keep) { sp = op; si = oi; }
      }
    }

    // inclusive prefix sum
    float c = sp;
#pragma unroll
    for (int off = 1; off < 64; off <<= 1) {
      float tp = __shfl_up(c, off);
      if (l >= off) c += tp;
    }

    unsigned long long m = __ballot(c >= 0.8f);
    int kv = (m == 0ULL) ? NEXP : __ffsll(m);

    // ambiguity flags (margins >> bf16-split logit error ~2e-5)
    float spn = __shfl_down(sp, 1);
    bool pairRisk = (l < kv) && (l < 63) && ((sp - spn) < 1e-3f * (sp + spn));
    bool cumRisk  = fabsf(c - 0.8f) < 3e-4f;
    bool flagged  = (__ballot(pairRisk || cumRisk) != 0ULL);

    bool sel = l < kv;
    const int tok = blockIdx.x * 64 + tl;
    size_t base = (size_t)tok * NEXP;
    out_exp[base + l]  = sel ? (float)si : -1.0f;
    out_prob[base + l] = sel ? sp : 0.0f;
    if (l == 0) {
      out_k[tok] = (float)kv;
      if (flagged) {
        unsigned int idx = atomicAdd(flag_count, 1u);
        flag_list[idx] = tok;
      }
    }
  }
}

// ---- Kernel 2: fp64 exact repair of flagged tokens -------------------------
__global__ __launch_bounds__(256) void router_repair(
    const float* __restrict__ x, const float* __restrict__ W,
    const float* __restrict__ b, const unsigned int* __restrict__ flag_count,
    const int* __restrict__ flag_list, float* __restrict__ out_exp,
    float* __restrict__ out_prob, float* __restrict__ out_k) {
  __shared__ double part[4][NEXP];
  const int t = threadIdx.x;
  const int e = t & 63;
  const int c = t >> 6;
  const int n = (int)*flag_count;

  for (int i = blockIdx.x; i < n; i += gridDim.x) {
    const int tok = flag_list[i];
    const float* xrow = x + (size_t)tok * HID;
    double s = 0.0;
    const int k0 = c * (HID / 4);
#pragma unroll 8
    for (int k = k0; k < k0 + HID / 4; ++k)
      s = fma((double)xrow[k], (double)W[(size_t)k * NEXP + e], s);
    part[c][e] = s;
    __syncthreads();

    if (t < 64) {
      double lgv = ((part[0][e] + part[1][e]) + part[2][e]) + part[3][e] +
                   (double)b[e];
      double mx = lgv;
#pragma unroll
      for (int off = 32; off; off >>= 1) mx = fmax(mx, __shfl_xor(mx, off));
      double ev = exp(lgv - mx);
      double sm = ev;
#pragma unroll
      for (int off = 32; off; off >>= 1) sm += __shfl_xor(sm, off);
      double p = ev / sm;

      double sp = p;
      int    si = e;
#pragma unroll
      for (int k = 2; k <= 64; k <<= 1) {
#pragma unroll
        for (int j = k >> 1; j > 0; j >>= 1) {
          double op = __shfl_xor(sp, j);
          int    oi = __shfl_xor(si, j);
          bool cmp  = (sp > op) || (sp == op && si < oi);
          bool keep = (cmp == (((e & k) == 0) == ((e & j) == 0)));
          if (!keep) { sp = op; si = oi; }
        }
      }

      double cc = sp;
#pragma unroll
      for (int off = 1; off < 64; off <<= 1) {
        double tp = __shfl_up(cc, off);
        if (e >= off) cc += tp;
      }

      unsigned long long m = __ballot(cc >= 0.8);
      int kv = (m == 0ULL) ? NEXP : __ffsll(m);

      bool sel = e < kv;
      size_t base = (size_t)tok * NEXP;
      out_exp[base + e]  = sel ? (float)si : -1.0f;
      out_prob[base + e] = sel ? (float)sp : 0.0f;
      if (e == 0) out_k[tok] = (float)kv;
    }
    __syncthreads();
  }
}

extern "C" void kernel_launch(void* const* d_in, const int* in_sizes, int n_in,
                              void* d_out, int out_size, void* d_ws,
                              size_t ws_size, hipStream_t stream) {
  const float* x = (const float*)d_in[0];
  const float* W = (const float*)d_in[1];
  const float* b = (const float*)d_in[2];

  float* out_exp  = (float*)d_out;
  float* out_prob = out_exp + (size_t)NTOK * NEXP;
  float* out_k    = out_prob + (size_t)NTOK * NEXP;

  short* wfh = (short*)d_ws;                                   // 512 KB
  short* wfl = (short*)((char*)d_ws + (size_t)512 * 1024);     // 512 KB
  unsigned int* flag_count = (unsigned int*)((char*)d_ws + (size_t)1024 * 1024);
  int* flag_list = (int*)((char*)d_ws + (size_t)1024 * 1024 + 256);

  hipMemsetAsync(flag_count, 0, 4, stream);

  wfrag_kernel<<<128, 256, 0, stream>>>(W, wfh, wfl);
  router_main<<<NTOK / 64, 256, 0, stream>>>(x, wfh, wfl, b, out_exp,
                                             out_prob, out_k, flag_count,
                                             flag_list);
  router_repair<<<128, 256, 0, stream>>>(x, W, b, flag_count, flag_list,
                                         out_exp, out_prob, out_k);
}

// Round 6
// 147.455 us; speedup vs baseline: 2.2246x; 1.2596x over previous
//
#include <hip/hip_runtime.h>
#include <math.h>

#define HID 4096
#define NEXP 64
#define NTOK 16384

typedef __attribute__((ext_vector_type(8))) short short8;
typedef __attribute__((ext_vector_type(8))) __bf16 bf16x8;
typedef __attribute__((ext_vector_type(4))) float f32x4;

// ---- Kernel 0: convert W[k][e] fp32 -> hi/lo bf16 in B-fragment-linear order
// Wfrag[((ks*4 + nt)*64 + lane)*8 + j] = W[ks*32 + (lane>>4)*8 + j][nt*16 + (lane&15)]
__global__ __launch_bounds__(256) void wfrag_kernel(
    const float* __restrict__ W, short* __restrict__ wfh,
    short* __restrict__ wfl) {
  int gid = blockIdx.x * 256 + threadIdx.x;  // 0 .. 32767
  int l  = gid & 63;
  int nt = (gid >> 6) & 3;
  int ks = gid >> 8;                         // 0 .. 127
  int e  = nt * 16 + (l & 15);
  int k0 = ks * 32 + (l >> 4) * 8;
  bf16x8 h8, l8;
#pragma unroll
  for (int j = 0; j < 8; ++j) {
    float w = W[(size_t)(k0 + j) * NEXP + e];
    __bf16 h = (__bf16)w;         // RNE
    h8[j] = h;
    l8[j] = (__bf16)(w - (float)h);
  }
  ((short8*)wfh)[gid] = __builtin_bit_cast(short8, h8);
  ((short8*)wfl)[gid] = __builtin_bit_cast(short8, l8);
}

// ---- Kernel 1: MFMA GEMM, K split across 4 waves + fp32 routing ------------
// Block = 16 tokens. Wave q computes K in [q*1024, (q+1)*1024); partial
// 16x64 fp32 tiles meet in LDS; routing reads summed logits.
__global__ __launch_bounds__(256, 4) void router_main(
    const float* __restrict__ x, const short* __restrict__ wfh,
    const short* __restrict__ wfl, const float* __restrict__ b,
    float* __restrict__ out_exp, float* __restrict__ out_prob,
    float* __restrict__ out_k, unsigned int* __restrict__ flag_count,
    int* __restrict__ flag_list) {
  __shared__ float partial[4][16][NEXP];  // 16 KB

  const int t = threadIdx.x;
  const int q = t >> 6;    // wave = K-quarter
  const int l = t & 63;    // lane
  const int m0 = blockIdx.x * 16;

  // A-frag source: row = m0 + (l&15), k = q*1024 + i*32 + (l>>4)*8 + j
  const float* xptr =
      x + (size_t)(m0 + (l & 15)) * HID + q * (HID / 4) + (l >> 4) * 8;
  const short8* wfh8 = (const short8*)wfh;
  const short8* wfl8 = (const short8*)wfl;

  f32x4 acc1[4], acc2[4];
#pragma unroll
  for (int nt = 0; nt < 4; ++nt) {
    acc1[nt] = (f32x4){0.f, 0.f, 0.f, 0.f};
    acc2[nt] = (f32x4){0.f, 0.f, 0.f, 0.f};
  }

#pragma unroll 4
  for (int i = 0; i < HID / 128; ++i) {   // 32 iters, K=32 each
    float xv[8];
    *(float4*)&xv[0] = *(const float4*)(xptr + i * 32);
    *(float4*)&xv[4] = *(const float4*)(xptr + i * 32 + 4);
    bf16x8 ah, al;
#pragma unroll
    for (int j = 0; j < 8; ++j) {
      __bf16 h = (__bf16)xv[j];          // v_cvt_pk_bf16_f32 pairs
      ah[j] = h;
      al[j] = (__bf16)(xv[j] - (float)h);
    }
    const int wbase = (q * 32 + i) * 256 + l;
#pragma unroll
    for (int nt = 0; nt < 4; ++nt) {
      bf16x8 bh = __builtin_bit_cast(bf16x8, wfh8[wbase + nt * 64]);
      bf16x8 bl = __builtin_bit_cast(bf16x8, wfl8[wbase + nt * 64]);
      acc1[nt] = __builtin_amdgcn_mfma_f32_16x16x32_bf16(ah, bh, acc1[nt], 0, 0, 0);
      acc2[nt] = __builtin_amdgcn_mfma_f32_16x16x32_bf16(al, bh, acc2[nt], 0, 0, 0);
      acc2[nt] = __builtin_amdgcn_mfma_f32_16x16x32_bf16(ah, bl, acc2[nt], 0, 0, 0);
      acc2[nt] = __builtin_amdgcn_mfma_f32_16x16x32_bf16(al, bl, acc2[nt], 0, 0, 0);
    }
  }

  // D layout: row (token) = (l>>4)*4 + r, col (expert) = nt*16 + (l&15)
#pragma unroll
  for (int nt = 0; nt < 4; ++nt)
#pragma unroll
    for (int r = 0; r < 4; ++r)
      partial[q][(l >> 4) * 4 + r][nt * 16 + (l & 15)] =
          acc1[nt][r] + acc2[nt][r];
  __syncthreads();

  // ---------------- routing (fp32; fp64 repair net catches close calls) ----
  const float bias = b[l];
  for (int it = 0; it < 4; ++it) {
    const int tl = q * 4 + it;   // wave q routes tokens q*4 .. q*4+3
    float lgv = (partial[0][tl][l] + partial[1][tl][l]) +
                (partial[2][tl][l] + partial[3][tl][l]) + bias;

    float mx = lgv;
#pragma unroll
    for (int off = 32; off; off >>= 1) mx = fmaxf(mx, __shfl_xor(mx, off));
    float ev = expf(lgv - mx);
    float sm = ev;
#pragma unroll
    for (int off = 32; off; off >>= 1) sm += __shfl_xor(sm, off);
    float p = ev / sm;

    // bitonic sort: descending by p, ties by ascending index
    float sp = p;
    int   si = l;
#pragma unroll
    for (int k = 2; k <= 64; k <<= 1) {
#pragma unroll
      for (int j = k >> 1; j > 0; j >>= 1) {
        float op = __shfl_xor(sp, j);
        int   oi = __shfl_xor(si, j);
        bool cmp  = (sp > op) || (sp == op && si < oi);
        bool keep = (cmp == (((l & k) == 0) == ((l & j) == 0)));
        if (!keep) { sp = op; si = oi; }
      }
    }

    // inclusive prefix sum
    float c = sp;
#pragma unroll
    for (int off = 1; off < 64; off <<= 1) {
      float tp = __shfl_up(c, off);
      if (l >= off) c += tp;
    }

    unsigned long long m = __ballot(c >= 0.8f);
    int kv = (m == 0ULL) ? NEXP : __ffsll(m);

    // ambiguity flags (margins >> split-bf16 logit error ~2e-5)
    float spn = __shfl_down(sp, 1);
    bool pairRisk = (l < kv) && (l < 63) && ((sp - spn) < 1e-3f * (sp + spn));
    bool cumRisk  = fabsf(c - 0.8f) < 3e-4f;
    bool flagged  = (__ballot(pairRisk || cumRisk) != 0ULL);

    bool sel = l < kv;
    const int tok = m0 + tl;
    size_t base = (size_t)tok * NEXP;
    out_exp[base + l]  = sel ? (float)si : -1.0f;
    out_prob[base + l] = sel ? sp : 0.0f;
    if (l == 0) {
      out_k[tok] = (float)kv;
      if (flagged) {
        unsigned int idx = atomicAdd(flag_count, 1u);
        flag_list[idx] = tok;
      }
    }
  }
}

// ---- Kernel 2: fp64 exact repair of flagged tokens -------------------------
__global__ __launch_bounds__(256) void router_repair(
    const float* __restrict__ x, const float* __restrict__ W,
    const float* __restrict__ b, const unsigned int* __restrict__ flag_count,
    const int* __restrict__ flag_list, float* __restrict__ out_exp,
    float* __restrict__ out_prob, float* __restrict__ out_k) {
  __shared__ double part[4][NEXP];
  const int t = threadIdx.x;
  const int e = t & 63;
  const int c = t >> 6;
  const int n = (int)*flag_count;

  for (int i = blockIdx.x; i < n; i += gridDim.x) {
    const int tok = flag_list[i];
    const float* xrow = x + (size_t)tok * HID;
    double s = 0.0;
    const int k0 = c * (HID / 4);
#pragma unroll 8
    for (int k = k0; k < k0 + HID / 4; ++k)
      s = fma((double)xrow[k], (double)W[(size_t)k * NEXP + e], s);
    part[c][e] = s;
    __syncthreads();

    if (t < 64) {
      double lgv = ((part[0][e] + part[1][e]) + part[2][e]) + part[3][e] +
                   (double)b[e];
      double mx = lgv;
#pragma unroll
      for (int off = 32; off; off >>= 1) mx = fmax(mx, __shfl_xor(mx, off));
      double ev = exp(lgv - mx);
      double sm = ev;
#pragma unroll
      for (int off = 32; off; off >>= 1) sm += __shfl_xor(sm, off);
      double p = ev / sm;

      double sp = p;
      int    si = e;
#pragma unroll
      for (int k = 2; k <= 64; k <<= 1) {
#pragma unroll
        for (int j = k >> 1; j > 0; j >>= 1) {
          double op = __shfl_xor(sp, j);
          int    oi = __shfl_xor(si, j);
          bool cmp  = (sp > op) || (sp == op && si < oi);
          bool keep = (cmp == (((e & k) == 0) == ((e & j) == 0)));
          if (!keep) { sp = op; si = oi; }
        }
      }

      double cc = sp;
#pragma unroll
      for (int off = 1; off < 64; off <<= 1) {
        double tp = __shfl_up(cc, off);
        if (e >= off) cc += tp;
      }

      unsigned long long m = __ballot(cc >= 0.8);
      int kv = (m == 0ULL) ? NEXP : __ffsll(m);

      bool sel = e < kv;
      size_t base = (size_t)tok * NEXP;
      out_exp[base + e]  = sel ? (float)si : -1.0f;
      out_prob[base + e] = sel ? (float)sp : 0.0f;
      if (e == 0) out_k[tok] = (float)kv;
    }
    __syncthreads();
  }
}

extern "C" void kernel_launch(void* const* d_in, const int* in_sizes, int n_in,
                              void* d_out, int out_size, void* d_ws,
                              size_t ws_size, hipStream_t stream) {
  const float* x = (const float*)d_in[0];
  const float* W = (const float*)d_in[1];
  const float* b = (const float*)d_in[2];

  float* out_exp  = (float*)d_out;
  float* out_prob = out_exp + (size_t)NTOK * NEXP;
  float* out_k    = out_prob + (size_t)NTOK * NEXP;

  short* wfh = (short*)d_ws;                                   // 512 KB
  short* wfl = (short*)((char*)d_ws + (size_t)512 * 1024);     // 512 KB
  unsigned int* flag_count = (unsigned int*)((char*)d_ws + (size_t)1024 * 1024);
  int* flag_list = (int*)((char*)d_ws + (size_t)1024 * 1024 + 256);

  hipMemsetAsync(flag_count, 0, 4, stream);

  wfrag_kernel<<<128, 256, 0, stream>>>(W, wfh, wfl);
  router_main<<<NTOK / 16, 256, 0, stream>>>(x, wfh, wfl, b, out_exp,
                                             out_prob, out_k, flag_count,
                                             flag_list);
  router_repair<<<128, 256, 0, stream>>>(x, W, b, flag_count, flag_list,
                                         out_exp, out_prob, out_k);
}